// Round 12
// baseline (115.232 us; speedup 1.0000x reference)
//
#include <hip/hip_runtime.h>
#include <math.h>

#define NEG_SLOPE 0.2f
#define EPS_F 1e-16f
#define CIN 128
#define HC 64
#define BSH 7              // bucket shift: 128 nodes per bucket
#define BNODES 128
#define NBKT 1024          // bucket count (tgt >> 7), max node 131071 (N < 2^17)
#define PBLK 256           // partition blocks
#define CSR_CAP 4096       // LDS csr capacity per bucket (avg ~2050, max ~2300)

typedef _Float16 f16;
typedef _Float16 f16x8 __attribute__((ext_vector_type(8)));
typedef float f32x4  __attribute__((ext_vector_type(4)));

// ---- P1: per-(block,bucket) histogram of tgt>>BSH (LDS atomics only) ------
__global__ __launch_bounds__(256) void p1_count(const int* __restrict__ tgt,
                                                int* __restrict__ cnt, int E, int EPB)
{
    __shared__ int lh[NBKT];
    for (int i = threadIdx.x; i < NBKT; i += 256) lh[i] = 0;
    __syncthreads();
    int e0 = blockIdx.x * EPB, e1 = min(E, e0 + EPB);
    for (int e = e0 + threadIdx.x; e < e1; e += 256)
        atomicAdd(&lh[((unsigned)tgt[e]) >> BSH], 1);
    __syncthreads();
    for (int b = threadIdx.x; b < NBKT; b += 256)
        cnt[b * PBLK + blockIdx.x] = lh[b];
}

// ---- scan level 1 ---------------------------------------------------------
__global__ __launch_bounds__(1024) void scan_block(const int* __restrict__ in,
                                                   int* __restrict__ out,
                                                   int* __restrict__ bsum, int M)
{
    __shared__ int s[1024];
    int i = blockIdx.x * 1024 + threadIdx.x;
    int v = (i < M) ? in[i] : 0;
    s[threadIdx.x] = v;
    __syncthreads();
    for (int d = 1; d < 1024; d <<= 1) {
        int t = (threadIdx.x >= (unsigned)d) ? s[threadIdx.x - d] : 0;
        __syncthreads();
        s[threadIdx.x] += t;
        __syncthreads();
    }
    if (i < M) out[i + 1] = s[threadIdx.x];
    if (threadIdx.x == 1023) bsum[blockIdx.x] = s[1023];
}

// ---- scan level 2 (fused) -------------------------------------------------
__global__ __launch_bounds__(1024) void scan_add2(int* __restrict__ out,
                                                  const int* __restrict__ bsum,
                                                  int M, int nb)
{
    __shared__ int sPre;
    int t = threadIdx.x;
    if (t < 64) {
        int sum = 0;
        for (int j = t; j < nb; j += 64)
            if (j < (int)blockIdx.x) sum += bsum[j];
        sum += __shfl_xor(sum, 1);  sum += __shfl_xor(sum, 2);
        sum += __shfl_xor(sum, 4);  sum += __shfl_xor(sum, 8);
        sum += __shfl_xor(sum, 16); sum += __shfl_xor(sum, 32);
        if (t == 0) sPre = sum;
    }
    __syncthreads();
    int pre = sPre;
    int i = blockIdx.x * 1024 + t;
    if (i < M) out[i + 1] += pre;
    if (i == 0) out[0] = 0;
}

// ---- fused: P3 partition (blocks [0,PBLK)) + projection (rest) ------------
// P3 role FIRST in the grid so it starts at t=0 and hides under proj compute.
__global__ __launch_bounds__(256) void proj_p3(
    const float* __restrict__ x, const float* __restrict__ W,
    const float* __restrict__ att, f16* __restrict__ h,
    float* __restrict__ asrc, float* __restrict__ atgt, int N,
    const int* __restrict__ src, const int* __restrict__ tgt,
    const int* __restrict__ matScan, int* __restrict__ pairs, int E, int EPB)
{
    __shared__ f16 sWt[HC][CIN + 8];
    __shared__ int lh[NBKT];

    if ((int)blockIdx.x < PBLK) {
        // ---- P3 role ----
        int pb = blockIdx.x;
        for (int i = threadIdx.x; i < NBKT; i += 256) lh[i] = 0;
        __syncthreads();
        int e0 = pb * EPB, e1 = min(E, e0 + EPB);
        for (int e = e0 + threadIdx.x; e < e1; e += 256) {
            int t = tgt[e];
            int bkt = ((unsigned)t) >> BSH;
            int r = atomicAdd(&lh[bkt], 1);
            int pos = matScan[bkt * PBLK + pb] + r;
            pairs[pos] = src[e] | ((t & (BNODES - 1)) << 17);
        }
        return;
    }

    // ---- proj role ----
    int rowBase = ((int)blockIdx.x - PBLK) * 64;
    for (int i = threadIdx.x; i < CIN * HC; i += 256) {
        int k = i >> 6, c = i & 63;
        sWt[c][k] = (f16)W[i];
    }
    __syncthreads();

    int lane = threadIdx.x & 63;
    int wv   = threadIdx.x >> 6;
    int mrow = lane & 15, g = lane >> 4;
    int r16  = rowBase + wv * 16;

    f16x8 bfrag[4][4];
#pragma unroll
    for (int nt = 0; nt < 4; ++nt)
#pragma unroll
        for (int kc = 0; kc < 4; ++kc)
            bfrag[nt][kc] = *reinterpret_cast<const f16x8*>(&sWt[nt * 16 + mrow][kc * 32 + g * 8]);

    int arow = r16 + mrow;
    const float* xr = x + (size_t)(arow < N ? arow : N - 1) * CIN;
    float4 xa[4][2];
#pragma unroll
    for (int kc = 0; kc < 4; ++kc) {
        xa[kc][0] = *reinterpret_cast<const float4*>(xr + kc * 32 + g * 8);
        xa[kc][1] = *reinterpret_cast<const float4*>(xr + kc * 32 + g * 8 + 4);
    }

    f32x4 acc[4] = {};
#pragma unroll
    for (int kc = 0; kc < 4; ++kc) {
        f16x8 a;
        a[0] = (f16)xa[kc][0].x; a[1] = (f16)xa[kc][0].y;
        a[2] = (f16)xa[kc][0].z; a[3] = (f16)xa[kc][0].w;
        a[4] = (f16)xa[kc][1].x; a[5] = (f16)xa[kc][1].y;
        a[6] = (f16)xa[kc][1].z; a[7] = (f16)xa[kc][1].w;
#pragma unroll
        for (int nt = 0; nt < 4; ++nt)
            acc[nt] = __builtin_amdgcn_mfma_f32_16x16x32_f16(a, bfrag[nt][kc], acc[nt], 0, 0, 0);
    }

#pragma unroll
    for (int nt = 0; nt < 4; ++nt) {
        int c = nt * 16 + mrow;
        float as_w = att[(c >> 3) * 16 + (c & 7)];
        float at_w = att[(c >> 3) * 16 + 8 + (c & 7)];
#pragma unroll
        for (int q = 0; q < 4; ++q) {
            int n = r16 + g * 4 + q;
            float v = acc[nt][q];
            if (n < N) h[(size_t)n * HC + c] = (f16)v;
            float vs = v * as_w, vt = v * at_w;
            vs += __shfl_xor(vs, 1); vs += __shfl_xor(vs, 2); vs += __shfl_xor(vs, 4);
            vt += __shfl_xor(vt, 1); vt += __shfl_xor(vt, 2); vt += __shfl_xor(vt, 4);
            if ((lane & 7) == 0 && n < N) {
                asrc[n * 8 + (c >> 3)] = vs;
                atgt[n * 8 + (c >> 3)] = vt;
            }
        }
    }
}

// ---- fused P4 + gather (r9 shape: 256 thr, 4 degree-sorted passes) --------
__global__ __launch_bounds__(256) void p4_gather(
    const int* __restrict__ pairs, const int* __restrict__ matScan,
    const f16* __restrict__ h, const float* __restrict__ asrc,
    const float* __restrict__ atgt, const float* __restrict__ bias,
    int* __restrict__ csr_g, float* __restrict__ out, int N)
{
    __shared__ int hist[BNODES], scanS[BNODES], fill[BNODES], order[BNODES];
    __shared__ int h2[64], s2[64];
    __shared__ int csrL[CSR_CAP];

    int b = blockIdx.x;
    int base = matScan[b * PBLK];
    int size = matScan[(b + 1) * PBLK] - base;
    int bN0 = b << BSH;
    int tid = threadIdx.x;
    bool lds_ok = (size <= CSR_CAP);

    if (tid < BNODES) { hist[tid] = 0; fill[tid] = 0; }
    else if (tid < BNODES + 64) h2[tid - BNODES] = 0;
    __syncthreads();

    for (int k = tid; k < size; k += 256)
        atomicAdd(&hist[((unsigned)pairs[base + k]) >> 17], 1);
    __syncthreads();

    int myrank = 0, mybin = 0;
    if (tid < BNODES) {
        scanS[tid] = hist[tid];
        mybin = min(hist[tid], 63);
        myrank = atomicAdd(&h2[mybin], 1);
    }
    __syncthreads();
    for (int d = 1; d < BNODES; d <<= 1) {
        int t = (tid >= (unsigned)d && tid < BNODES) ? scanS[tid - d] : 0;
        __syncthreads();
        if (tid < BNODES) scanS[tid] += t;
        __syncthreads();
    }

    if (tid == 0) {
        int run = 0;
        for (int i = 0; i < 64; ++i) { int t = h2[i]; s2[i] = run; run += t; }
    }
    if (lds_ok) {
        for (int k = tid; k < size; k += 256) {
            int p = pairs[base + k];
            int j = ((unsigned)p) >> 17;
            int r = atomicAdd(&fill[j], 1);
            csrL[scanS[j] - hist[j] + r] = p & 0x1FFFF;
        }
    } else {
        for (int k = tid; k < size; k += 256) {
            int p = pairs[base + k];
            int j = ((unsigned)p) >> 17;
            int r = atomicAdd(&fill[j], 1);
            csr_g[base + scanS[j] - hist[j] + r] = p & 0x1FFFF;
        }
    }
    __syncthreads();
    if (tid < BNODES) order[s2[mybin] + myrank] = tid;
    __syncthreads();

    // ---- gather: 4 passes x 32 degree-adjacent nodes, 8 lanes/node ----
    unsigned lh8 = tid & 7;
    unsigned c0  = lh8 * 8u;

#define EDGE_ACC(S)                                                           \
    { unsigned Su = (unsigned)(S);                                            \
      float Aa = asrc[Su * 8u + lh8] + at;                                    \
      f16x8 Hh = *reinterpret_cast<const f16x8*>(&h[Su * 64u + c0]);          \
      Aa = fmaxf(Aa, NEG_SLOPE * Aa);                                         \
      float Ww = __expf(Aa);                                                  \
      ssum += Ww;                                                             \
      _Pragma("unroll")                                                       \
      for (int i = 0; i < 8; ++i) acc[i] += Ww * (float)Hh[i]; }

#define GBODY(CSRLD)                                                          \
    for (; k + 8 <= k1; k += 8) {                                             \
        unsigned S0 = (unsigned)CSRLD(k),     S1 = (unsigned)CSRLD(k + 1);    \
        unsigned S2 = (unsigned)CSRLD(k + 2), S3 = (unsigned)CSRLD(k + 3);    \
        unsigned S4 = (unsigned)CSRLD(k + 4), S5 = (unsigned)CSRLD(k + 5);    \
        unsigned S6 = (unsigned)CSRLD(k + 6), S7 = (unsigned)CSRLD(k + 7);    \
        float A0 = asrc[S0 * 8u + lh8], A1 = asrc[S1 * 8u + lh8];             \
        float A2 = asrc[S2 * 8u + lh8], A3 = asrc[S3 * 8u + lh8];             \
        float A4 = asrc[S4 * 8u + lh8], A5 = asrc[S5 * 8u + lh8];             \
        float A6 = asrc[S6 * 8u + lh8], A7 = asrc[S7 * 8u + lh8];             \
        f16x8 H0 = *reinterpret_cast<const f16x8*>(&h[S0 * 64u + c0]);        \
        f16x8 H1 = *reinterpret_cast<const f16x8*>(&h[S1 * 64u + c0]);        \
        f16x8 H2 = *reinterpret_cast<const f16x8*>(&h[S2 * 64u + c0]);        \
        f16x8 H3 = *reinterpret_cast<const f16x8*>(&h[S3 * 64u + c0]);        \
        f16x8 H4 = *reinterpret_cast<const f16x8*>(&h[S4 * 64u + c0]);        \
        f16x8 H5 = *reinterpret_cast<const f16x8*>(&h[S5 * 64u + c0]);        \
        f16x8 H6 = *reinterpret_cast<const f16x8*>(&h[S6 * 64u + c0]);        \
        f16x8 H7 = *reinterpret_cast<const f16x8*>(&h[S7 * 64u + c0]);        \
        A0 += at; A1 += at; A2 += at; A3 += at;                               \
        A4 += at; A5 += at; A6 += at; A7 += at;                               \
        A0 = fmaxf(A0, NEG_SLOPE * A0); A1 = fmaxf(A1, NEG_SLOPE * A1);       \
        A2 = fmaxf(A2, NEG_SLOPE * A2); A3 = fmaxf(A3, NEG_SLOPE * A3);       \
        A4 = fmaxf(A4, NEG_SLOPE * A4); A5 = fmaxf(A5, NEG_SLOPE * A5);       \
        A6 = fmaxf(A6, NEG_SLOPE * A6); A7 = fmaxf(A7, NEG_SLOPE * A7);       \
        float w0 = __expf(A0), w1 = __expf(A1);                               \
        float w2 = __expf(A2), w3 = __expf(A3);                               \
        float w4 = __expf(A4), w5 = __expf(A5);                               \
        float w6 = __expf(A6), w7 = __expf(A7);                               \
        ssum += ((w0 + w1) + (w2 + w3)) + ((w4 + w5) + (w6 + w7));            \
        _Pragma("unroll")                                                     \
        for (int i = 0; i < 8; ++i)                                           \
            acc[i] += ((w0 * (float)H0[i] + w1 * (float)H1[i])                \
                     + (w2 * (float)H2[i] + w3 * (float)H3[i]))               \
                    + ((w4 * (float)H4[i] + w5 * (float)H5[i])                \
                     + (w6 * (float)H6[i] + w7 * (float)H7[i]));              \
    }                                                                         \
    for (; k < k1; ++k) { EDGE_ACC(CSRLD(k)); }

    for (int g = 0; g < BNODES; g += 32) {
        int ln   = order[g + (tid >> 3)];
        int node = bN0 + ln;
        if (node >= N) continue;
        int k1 = scanS[ln];
        int k  = k1 - hist[ln];
        float at = atgt[(unsigned)node * 8u + lh8];
        float ssum = 0.f;
        float acc[8] = {0.f, 0.f, 0.f, 0.f, 0.f, 0.f, 0.f, 0.f};

        if (lds_ok) {
#define CLD(i) csrL[i]
            GBODY(CLD)
#undef CLD
        } else {
#define CGD(i) csr_g[base + (i)]
            GBODY(CGD)
#undef CGD
        }

        float inv = 1.f / fmaxf(ssum, EPS_F);
        float4 b0 = *reinterpret_cast<const float4*>(&bias[c0]);
        float4 b1 = *reinterpret_cast<const float4*>(&bias[c0 + 4]);
        float4 o0, o1;
        o0.x = acc[0] * inv + b0.x; o0.y = acc[1] * inv + b0.y;
        o0.z = acc[2] * inv + b0.z; o0.w = acc[3] * inv + b0.w;
        o1.x = acc[4] * inv + b1.x; o1.y = acc[5] * inv + b1.y;
        o1.z = acc[6] * inv + b1.z; o1.w = acc[7] * inv + b1.w;
        float* op = &out[(size_t)node * HC + c0];
        *reinterpret_cast<float4*>(op)     = o0;
        *reinterpret_cast<float4*>(op + 4) = o1;
    }
}

extern "C" void kernel_launch(void* const* d_in, const int* in_sizes, int n_in,
                              void* d_out, int out_size, void* d_ws, size_t ws_size,
                              hipStream_t stream)
{
    const float* x    = (const float*)d_in[0];
    const int*   ei   = (const int*)d_in[1];
    const float* W    = (const float*)d_in[2];
    const float* att  = (const float*)d_in[3];
    const float* bias = (const float*)d_in[4];
    float* out = (float*)d_out;

    int N = in_sizes[0] / CIN;
    int E = in_sizes[1] / 2;
    const int* src = ei;
    const int* tgt = ei + E;

    const int M = NBKT * PBLK;                    // 262144 count-matrix entries

    // workspace carve-up (~34 MB)
    f16*   h       = (f16*)d_ws;                  // N*64 fp16       (12.8 MB)
    float* asrc    = (float*)(h + (size_t)N * HC);// N*8             (3.2 MB)
    float* atgt    = asrc + (size_t)N * 8;        // N*8             (3.2 MB)
    int*   cnt     = (int*)(atgt + (size_t)N * 8);// M               (1 MB)
    int*   matScan = cnt + M;                     // M+1             (1 MB)
    int*   bsum    = matScan + M + 2;             // 256
    int*   pairs   = bsum + 1024;                 // E               (6.4 MB)
    int*   csr_g   = pairs + E;                   // E fallback      (6.4 MB)

    int EPB = (E + PBLK - 1) / PBLK;
    int projB = (N + 63) / 64;

    p1_count<<<PBLK, 256, 0, stream>>>(tgt, cnt, E, EPB);

    scan_block<<<M / 1024, 1024, 0, stream>>>(cnt, matScan, bsum, M);
    scan_add2<<<M / 1024, 1024, 0, stream>>>(matScan, bsum, M, M / 1024);

    proj_p3<<<PBLK + projB, 256, 0, stream>>>(x, W, att, h, asrc, atgt, N,
                                              src, tgt, matScan, pairs, E, EPB);

    p4_gather<<<(N + BNODES - 1) / BNODES, 256, 0, stream>>>(
        pairs, matScan, h, asrc, atgt, bias, csr_g, out, N);
}

// Round 13
// 112.039 us; speedup vs baseline: 1.0285x; 1.0285x over previous
//
#include <hip/hip_runtime.h>
#include <math.h>

#define NEG_SLOPE 0.2f
#define EPS_F 1e-16f
#define CIN 128
#define HC 64
#define BSH 7              // bucket shift: 128 nodes per bucket
#define BNODES 128
#define NBKT 1024          // bucket count (tgt >> 7), max node 131071 (N < 2^17)
#define PBLK 256           // partition blocks
#define CSR_CAP 4096       // LDS csr capacity per bucket (avg ~2050, max ~2300)
#define P3_CAP 6400        // LDS edge buffer per partition block (E/PBLK = 6250)

typedef _Float16 f16;
typedef _Float16 f16x8 __attribute__((ext_vector_type(8)));
typedef float f32x4  __attribute__((ext_vector_type(4)));

// ---- fused: projection (fp16 MFMA) + P1 bucket histogram (LDS atomics) ----
// cnt is BLOCK-MAJOR: cnt[pb*NBKT + bkt] -> contiguous writes per p1 block.
__global__ __launch_bounds__(256) void proj_p1(
    const float* __restrict__ x, const float* __restrict__ W,
    const float* __restrict__ att, f16* __restrict__ h,
    float* __restrict__ asrc, float* __restrict__ atgt, int N,
    const int* __restrict__ tgt, int* __restrict__ cnt, int E, int EPB,
    int projB)
{
    __shared__ f16 sWt[HC][CIN + 8];
    __shared__ int lh[NBKT];

    if ((int)blockIdx.x >= projB) {
        int pb = blockIdx.x - projB;
        for (int i = threadIdx.x; i < NBKT; i += 256) lh[i] = 0;
        __syncthreads();
        int e0 = pb * EPB, e1 = min(E, e0 + EPB);
        for (int e = e0 + threadIdx.x; e < e1; e += 256)
            atomicAdd(&lh[((unsigned)tgt[e]) >> BSH], 1);
        __syncthreads();
        for (int b = threadIdx.x; b < NBKT; b += 256)
            cnt[(size_t)pb * NBKT + b] = lh[b];
        return;
    }

    int rowBase = blockIdx.x * 64;
    for (int i = threadIdx.x; i < CIN * HC; i += 256) {
        int k = i >> 6, c = i & 63;
        sWt[c][k] = (f16)W[i];
    }
    __syncthreads();

    int lane = threadIdx.x & 63;
    int wv   = threadIdx.x >> 6;
    int mrow = lane & 15, g = lane >> 4;
    int r16  = rowBase + wv * 16;

    f16x8 bfrag[4][4];
#pragma unroll
    for (int nt = 0; nt < 4; ++nt)
#pragma unroll
        for (int kc = 0; kc < 4; ++kc)
            bfrag[nt][kc] = *reinterpret_cast<const f16x8*>(&sWt[nt * 16 + mrow][kc * 32 + g * 8]);

    int arow = r16 + mrow;
    const float* xr = x + (size_t)(arow < N ? arow : N - 1) * CIN;
    float4 xa[4][2];
#pragma unroll
    for (int kc = 0; kc < 4; ++kc) {
        xa[kc][0] = *reinterpret_cast<const float4*>(xr + kc * 32 + g * 8);
        xa[kc][1] = *reinterpret_cast<const float4*>(xr + kc * 32 + g * 8 + 4);
    }

    f32x4 acc[4] = {};
#pragma unroll
    for (int kc = 0; kc < 4; ++kc) {
        f16x8 a;
        a[0] = (f16)xa[kc][0].x; a[1] = (f16)xa[kc][0].y;
        a[2] = (f16)xa[kc][0].z; a[3] = (f16)xa[kc][0].w;
        a[4] = (f16)xa[kc][1].x; a[5] = (f16)xa[kc][1].y;
        a[6] = (f16)xa[kc][1].z; a[7] = (f16)xa[kc][1].w;
#pragma unroll
        for (int nt = 0; nt < 4; ++nt)
            acc[nt] = __builtin_amdgcn_mfma_f32_16x16x32_f16(a, bfrag[nt][kc], acc[nt], 0, 0, 0);
    }

#pragma unroll
    for (int nt = 0; nt < 4; ++nt) {
        int c = nt * 16 + mrow;
        float as_w = att[(c >> 3) * 16 + (c & 7)];
        float at_w = att[(c >> 3) * 16 + 8 + (c & 7)];
#pragma unroll
        for (int q = 0; q < 4; ++q) {
            int n = r16 + g * 4 + q;
            float v = acc[nt][q];
            if (n < N) h[(size_t)n * HC + c] = (f16)v;
            float vs = v * as_w, vt = v * at_w;
            vs += __shfl_xor(vs, 1); vs += __shfl_xor(vs, 2); vs += __shfl_xor(vs, 4);
            vt += __shfl_xor(vt, 1); vt += __shfl_xor(vt, 2); vt += __shfl_xor(vt, 4);
            if ((lane & 7) == 0 && n < N) {
                asrc[n * 8 + (c >> 3)] = vs;
                atgt[n * 8 + (c >> 3)] = vt;
            }
        }
    }
}

// ---- scan level 1 ---------------------------------------------------------
__global__ __launch_bounds__(1024) void scan_block(const int* __restrict__ in,
                                                   int* __restrict__ out,
                                                   int* __restrict__ bsum, int M)
{
    __shared__ int s[1024];
    int i = blockIdx.x * 1024 + threadIdx.x;
    int v = (i < M) ? in[i] : 0;
    s[threadIdx.x] = v;
    __syncthreads();
    for (int d = 1; d < 1024; d <<= 1) {
        int t = (threadIdx.x >= (unsigned)d) ? s[threadIdx.x - d] : 0;
        __syncthreads();
        s[threadIdx.x] += t;
        __syncthreads();
    }
    if (i < M) out[i + 1] = s[threadIdx.x];
    if (threadIdx.x == 1023) bsum[blockIdx.x] = s[1023];
}

// ---- scan level 2 (fused) -------------------------------------------------
__global__ __launch_bounds__(1024) void scan_add2(int* __restrict__ out,
                                                  const int* __restrict__ bsum,
                                                  int M, int nb)
{
    __shared__ int sPre;
    int t = threadIdx.x;
    if (t < 64) {
        int sum = 0;
        for (int j = t; j < nb; j += 64)
            if (j < (int)blockIdx.x) sum += bsum[j];
        sum += __shfl_xor(sum, 1);  sum += __shfl_xor(sum, 2);
        sum += __shfl_xor(sum, 4);  sum += __shfl_xor(sum, 8);
        sum += __shfl_xor(sum, 16); sum += __shfl_xor(sum, 32);
        if (t == 0) sPre = sum;
    }
    __syncthreads();
    int pre = sPre;
    int i = blockIdx.x * 1024 + t;
    if (i < M) out[i + 1] += pre;
    if (i == 0) out[0] = 0;
}

// ---- P3: LDS counting-sort per block, CONTIGUOUS coalesced global write ---
// Block pb's region = pairs[matScan[pb*NBKT] .. ), sorted by bucket inside.
__global__ __launch_bounds__(256) void p3_partition(
    const int* __restrict__ src, const int* __restrict__ tgt,
    const int* __restrict__ matScan, int* __restrict__ pairs, int E, int EPB)
{
    __shared__ int cur[NBKT];
    __shared__ int lbuf[P3_CAP];
    int pb  = blockIdx.x;
    int tid = threadIdx.x;
    int gbase = matScan[(size_t)pb * NBKT];
    for (int i = tid; i < NBKT; i += 256)
        cur[i] = matScan[(size_t)pb * NBKT + i] - gbase;
    __syncthreads();
    int e0 = pb * EPB, e1 = min(E, e0 + EPB);
    int sz = e1 - e0;
    if (sz <= P3_CAP) {
        for (int e = e0 + tid; e < e1; e += 256) {
            int t = tgt[e];
            int r = atomicAdd(&cur[((unsigned)t) >> BSH], 1);
            lbuf[r] = src[e] | ((t & (BNODES - 1)) << 17);
        }
        __syncthreads();
        for (int i = tid; i < sz; i += 256) pairs[gbase + i] = lbuf[i];
    } else {
        // fallback: direct scattered write (correct, slower; not expected)
        for (int e = e0 + tid; e < e1; e += 256) {
            int t = tgt[e];
            int r = atomicAdd(&cur[((unsigned)t) >> BSH], 1);
            pairs[gbase + r] = src[e] | ((t & (BNODES - 1)) << 17);
        }
    }
}

// ---- fused P4 + gather: segment assembly in LDS, degree-ordered gather ----
__global__ __launch_bounds__(256) void p4_gather(
    const int* __restrict__ pairs, const int* __restrict__ matScan,
    const f16* __restrict__ h, const float* __restrict__ asrc,
    const float* __restrict__ atgt, const float* __restrict__ bias,
    float* __restrict__ out, int N)
{
    __shared__ int segB[PBLK], segL[PBLK], segO[PBLK];
    __shared__ int hist[BNODES], scanS[BNODES], fill[BNODES], order[BNODES];
    __shared__ int h2[64], s2[64];
    __shared__ int csrT[CSR_CAP], csrL[CSR_CAP];

    int b   = blockIdx.x;
    int tid = threadIdx.x;
    int bN0 = b << BSH;

    // segment descriptors: block-major matScan, one segment per partition blk
    {
        int s0 = matScan[(size_t)tid * NBKT + b];
        int s1 = matScan[(size_t)tid * NBKT + b + 1];
        segB[tid] = s0;
        segL[tid] = s1 - s0;
        segO[tid] = s1 - s0;
    }
    __syncthreads();
    for (int d = 1; d < PBLK; d <<= 1) {
        int t = (tid >= d) ? segO[tid - d] : 0;
        __syncthreads();
        segO[tid] += t;
        __syncthreads();
    }
    int size = segO[PBLK - 1];
    bool lds_ok = (size <= CSR_CAP);

    unsigned lh8 = tid & 7;
    unsigned c0  = lh8 * 8u;

#define EDGE_ACC(S)                                                           \
    { unsigned Su = (unsigned)(S);                                            \
      float Aa = asrc[Su * 8u + lh8] + at;                                    \
      f16x8 Hh = *reinterpret_cast<const f16x8*>(&h[Su * 64u + c0]);          \
      Aa = fmaxf(Aa, NEG_SLOPE * Aa);                                         \
      float Ww = __expf(Aa);                                                  \
      ssum += Ww;                                                             \
      _Pragma("unroll")                                                       \
      for (int i = 0; i < 8; ++i) acc[i] += Ww * (float)Hh[i]; }

#define WRITE_OUT(NODE)                                                       \
    { float inv = 1.f / fmaxf(ssum, EPS_F);                                   \
      float4 b0 = *reinterpret_cast<const float4*>(&bias[c0]);                \
      float4 b1 = *reinterpret_cast<const float4*>(&bias[c0 + 4]);            \
      float4 o0, o1;                                                          \
      o0.x = acc[0] * inv + b0.x; o0.y = acc[1] * inv + b0.y;                 \
      o0.z = acc[2] * inv + b0.z; o0.w = acc[3] * inv + b0.w;                 \
      o1.x = acc[4] * inv + b1.x; o1.y = acc[5] * inv + b1.y;                 \
      o1.z = acc[6] * inv + b1.z; o1.w = acc[7] * inv + b1.w;                 \
      float* op = &out[(size_t)(NODE) * HC + c0];                             \
      *reinterpret_cast<float4*>(op)     = o0;                                \
      *reinterpret_cast<float4*>(op + 4) = o1; }

    if (lds_ok) {
        // assemble bucket csr in LDS (deterministic segment order)
        {
            int L = segL[tid], B = segB[tid], O = segO[tid] - L;
            int i = 0;
            for (; i + 4 <= L; i += 4) {
                int a0 = pairs[B + i],     a1 = pairs[B + i + 1];
                int a2 = pairs[B + i + 2], a3 = pairs[B + i + 3];
                csrT[O + i] = a0;     csrT[O + i + 1] = a1;
                csrT[O + i + 2] = a2; csrT[O + i + 3] = a3;
            }
            for (; i < L; ++i) csrT[O + i] = pairs[B + i];
        }
        if (tid < BNODES) { hist[tid] = 0; fill[tid] = 0; }
        else if (tid < BNODES + 64) h2[tid - BNODES] = 0;
        __syncthreads();

        for (int k = tid; k < size; k += 256)
            atomicAdd(&hist[((unsigned)csrT[k]) >> 17], 1);
        __syncthreads();

        int myrank = 0, mybin = 0;
        if (tid < BNODES) {
            scanS[tid] = hist[tid];
            mybin = min(hist[tid], 63);
            myrank = atomicAdd(&h2[mybin], 1);
        }
        __syncthreads();
        for (int d = 1; d < BNODES; d <<= 1) {
            int t = (tid >= (unsigned)d && tid < BNODES) ? scanS[tid - d] : 0;
            __syncthreads();
            if (tid < BNODES) scanS[tid] += t;
            __syncthreads();
        }
        if (tid == 0) {
            int run = 0;
            for (int i = 0; i < 64; ++i) { int t = h2[i]; s2[i] = run; run += t; }
        }
        for (int k = tid; k < size; k += 256) {
            int p = csrT[k];
            int j = ((unsigned)p) >> 17;
            int r = atomicAdd(&fill[j], 1);
            csrL[scanS[j] - hist[j] + r] = p & 0x1FFFF;
        }
        __syncthreads();
        if (tid < BNODES) order[s2[mybin] + myrank] = tid;
        __syncthreads();

        // 4 passes x 32 degree-adjacent nodes, 8 lanes/node, 8-deep unroll
        for (int g = 0; g < BNODES; g += 32) {
            int ln   = order[g + (tid >> 3)];
            int node = bN0 + ln;
            if (node >= N) continue;
            int k1 = scanS[ln];
            int k  = k1 - hist[ln];
            float at = atgt[(unsigned)node * 8u + lh8];
            float ssum = 0.f;
            float acc[8] = {0.f, 0.f, 0.f, 0.f, 0.f, 0.f, 0.f, 0.f};

            for (; k + 8 <= k1; k += 8) {
                unsigned S0 = (unsigned)csrL[k],     S1 = (unsigned)csrL[k + 1];
                unsigned S2 = (unsigned)csrL[k + 2], S3 = (unsigned)csrL[k + 3];
                unsigned S4 = (unsigned)csrL[k + 4], S5 = (unsigned)csrL[k + 5];
                unsigned S6 = (unsigned)csrL[k + 6], S7 = (unsigned)csrL[k + 7];
                float A0 = asrc[S0 * 8u + lh8], A1 = asrc[S1 * 8u + lh8];
                float A2 = asrc[S2 * 8u + lh8], A3 = asrc[S3 * 8u + lh8];
                float A4 = asrc[S4 * 8u + lh8], A5 = asrc[S5 * 8u + lh8];
                float A6 = asrc[S6 * 8u + lh8], A7 = asrc[S7 * 8u + lh8];
                f16x8 H0 = *reinterpret_cast<const f16x8*>(&h[S0 * 64u + c0]);
                f16x8 H1 = *reinterpret_cast<const f16x8*>(&h[S1 * 64u + c0]);
                f16x8 H2 = *reinterpret_cast<const f16x8*>(&h[S2 * 64u + c0]);
                f16x8 H3 = *reinterpret_cast<const f16x8*>(&h[S3 * 64u + c0]);
                f16x8 H4 = *reinterpret_cast<const f16x8*>(&h[S4 * 64u + c0]);
                f16x8 H5 = *reinterpret_cast<const f16x8*>(&h[S5 * 64u + c0]);
                f16x8 H6 = *reinterpret_cast<const f16x8*>(&h[S6 * 64u + c0]);
                f16x8 H7 = *reinterpret_cast<const f16x8*>(&h[S7 * 64u + c0]);
                A0 += at; A1 += at; A2 += at; A3 += at;
                A4 += at; A5 += at; A6 += at; A7 += at;
                A0 = fmaxf(A0, NEG_SLOPE * A0); A1 = fmaxf(A1, NEG_SLOPE * A1);
                A2 = fmaxf(A2, NEG_SLOPE * A2); A3 = fmaxf(A3, NEG_SLOPE * A3);
                A4 = fmaxf(A4, NEG_SLOPE * A4); A5 = fmaxf(A5, NEG_SLOPE * A5);
                A6 = fmaxf(A6, NEG_SLOPE * A6); A7 = fmaxf(A7, NEG_SLOPE * A7);
                float w0 = __expf(A0), w1 = __expf(A1);
                float w2 = __expf(A2), w3 = __expf(A3);
                float w4 = __expf(A4), w5 = __expf(A5);
                float w6 = __expf(A6), w7 = __expf(A7);
                ssum += ((w0 + w1) + (w2 + w3)) + ((w4 + w5) + (w6 + w7));
#pragma unroll
                for (int i = 0; i < 8; ++i)
                    acc[i] += ((w0 * (float)H0[i] + w1 * (float)H1[i])
                             + (w2 * (float)H2[i] + w3 * (float)H3[i]))
                            + ((w4 * (float)H4[i] + w5 * (float)H5[i])
                             + (w6 * (float)H6[i] + w7 * (float)H7[i]));
            }
            for (; k < k1; ++k) { EDGE_ACC(csrL[k]); }

            WRITE_OUT(node)
        }
    } else {
        // slow correct fallback: scan all segments per node group (never expected)
        for (int g = 0; g < BNODES; g += 32) {
            int ln   = g + (tid >> 3);
            int node = bN0 + ln;
            if (node >= N) continue;
            float at = atgt[(unsigned)node * 8u + lh8];
            float ssum = 0.f;
            float acc[8] = {0.f, 0.f, 0.f, 0.f, 0.f, 0.f, 0.f, 0.f};
            for (int pb = 0; pb < PBLK; ++pb) {
                int B = segB[pb], L = segL[pb];
                for (int i = 0; i < L; ++i) {
                    int p = pairs[B + i];
                    if ((((unsigned)p) >> 17) == (unsigned)ln) { EDGE_ACC(p & 0x1FFFF); }
                }
            }
            WRITE_OUT(node)
        }
    }
}

extern "C" void kernel_launch(void* const* d_in, const int* in_sizes, int n_in,
                              void* d_out, int out_size, void* d_ws, size_t ws_size,
                              hipStream_t stream)
{
    const float* x    = (const float*)d_in[0];
    const int*   ei   = (const int*)d_in[1];
    const float* W    = (const float*)d_in[2];
    const float* att  = (const float*)d_in[3];
    const float* bias = (const float*)d_in[4];
    float* out = (float*)d_out;

    int N = in_sizes[0] / CIN;
    int E = in_sizes[1] / 2;
    const int* src = ei;
    const int* tgt = ei + E;

    const int M = NBKT * PBLK;                    // 262144 count-matrix entries

    // workspace carve-up (~28 MB)
    f16*   h       = (f16*)d_ws;                  // N*64 fp16       (12.8 MB)
    float* asrc    = (float*)(h + (size_t)N * HC);// N*8             (3.2 MB)
    float* atgt    = asrc + (size_t)N * 8;        // N*8             (3.2 MB)
    int*   cnt     = (int*)(atgt + (size_t)N * 8);// M               (1 MB)
    int*   matScan = cnt + M;                     // M+2             (1 MB)
    int*   bsum    = matScan + M + 2;             // 256
    int*   pairs   = bsum + 1024;                 // E               (6.4 MB)

    int EPB = (E + PBLK - 1) / PBLK;
    int projB = (N + 63) / 64;

    proj_p1<<<projB + PBLK, 256, 0, stream>>>(x, W, att, h, asrc, atgt, N,
                                              tgt, cnt, E, EPB, projB);

    scan_block<<<M / 1024, 1024, 0, stream>>>(cnt, matScan, bsum, M);
    scan_add2<<<M / 1024, 1024, 0, stream>>>(matScan, bsum, M, M / 1024);

    p3_partition<<<PBLK, 256, 0, stream>>>(src, tgt, matScan, pairs, E, EPB);

    p4_gather<<<(N + BNODES - 1) / BNODES, 256, 0, stream>>>(
        pairs, matScan, h, asrc, atgt, bias, out, N);
}

// Round 14
// 103.249 us; speedup vs baseline: 1.1161x; 1.0851x over previous
//
#include <hip/hip_runtime.h>
#include <math.h>

#define NEG_SLOPE 0.2f
#define EPS_F 1e-16f
#define CIN 128
#define HC 64
#define BSH 7              // bucket shift: 128 nodes per bucket
#define BNODES 128
#define NBKT 1024          // bucket count (tgt >> 7), max node 131071 (N < 2^17)
#define PBLK 256           // partition blocks
#define OSTR (NBKT + 1)    // offs row stride
#define CSR_CAP 4096       // LDS csr capacity per bucket (avg ~2050, max ~2300)

typedef _Float16 f16;
typedef _Float16 f16x8 __attribute__((ext_vector_type(8)));
typedef float f32x4  __attribute__((ext_vector_type(4)));

// ---- fused: P3 partition (blocks [0,PBLK)) + projection (rest) ------------
// Block-major pairs: block pb owns pairs[pb*EPB ..), sorted by bucket inside.
// p3 needs NO global scan: region base = pb*EPB; internal offsets via LDS scan.
// LDS roles overlay in one union buffer (17.4 KB).
__global__ __launch_bounds__(256) void proj_p3(
    const float* __restrict__ x, const float* __restrict__ W,
    const float* __restrict__ att, f16* __restrict__ h,
    float* __restrict__ asrc, float* __restrict__ atgt, int N,
    const int* __restrict__ src, const int* __restrict__ tgt,
    int* __restrict__ offs, int* __restrict__ pairs, int E, int EPB)
{
    __shared__ __align__(16) char smem[HC * (CIN + 8) * 2];   // 17408 B union

    if ((int)blockIdx.x < PBLK) {
        // ---- P3 role ----
        int* lh    = (int*)smem;          // [1024] counts -> cursors
        int* scanP = lh + NBKT;           // [256]
        int pb = blockIdx.x, tid = threadIdx.x;
        for (int i = tid; i < NBKT; i += 256) lh[i] = 0;
        __syncthreads();
        int e0 = pb * EPB, e1 = min(E, e0 + EPB), sz = e1 - e0;
        for (int e = e0 + tid; e < e1; e += 256)
            atomicAdd(&lh[((unsigned)tgt[e]) >> BSH], 1);
        __syncthreads();
        // exclusive scan of 1024 bins: 4 bins/thread + 256-wide Hillis-Steele
        int b4 = tid * 4;
        int v0 = lh[b4], v1 = lh[b4 + 1], v2 = lh[b4 + 2], v3 = lh[b4 + 3];
        int s4 = v0 + v1 + v2 + v3;
        scanP[tid] = s4;
        __syncthreads();
        for (int d = 1; d < 256; d <<= 1) {
            int t = (tid >= d) ? scanP[tid - d] : 0;
            __syncthreads();
            scanP[tid] += t;
            __syncthreads();
        }
        int base = scanP[tid] - s4;
        __syncthreads();
        int eo0 = base, eo1 = base + v0, eo2 = eo1 + v1, eo3 = eo2 + v2;
        lh[b4] = eo0; lh[b4 + 1] = eo1; lh[b4 + 2] = eo2; lh[b4 + 3] = eo3;
        size_t ob = (size_t)pb * OSTR + b4;
        offs[ob] = eo0; offs[ob + 1] = eo1; offs[ob + 2] = eo2; offs[ob + 3] = eo3;
        if (tid == 0) offs[(size_t)pb * OSTR + NBKT] = sz;
        __syncthreads();
        // scatter within own contiguous region (L2 absorbs in-window RMW)
        for (int e = e0 + tid; e < e1; e += 256) {
            int t = tgt[e];
            int r = atomicAdd(&lh[((unsigned)t) >> BSH], 1);
            pairs[e0 + r] = src[e] | ((t & (BNODES - 1)) << 17);
        }
        return;
    }

    // ---- proj role ----
    f16 (*sWt)[CIN + 8] = (f16(*)[CIN + 8])smem;
    int rowBase = ((int)blockIdx.x - PBLK) * 64;
    for (int i = threadIdx.x; i < CIN * HC; i += 256) {
        int k = i >> 6, c = i & 63;
        sWt[c][k] = (f16)W[i];
    }
    __syncthreads();

    int lane = threadIdx.x & 63;
    int wv   = threadIdx.x >> 6;
    int mrow = lane & 15, g = lane >> 4;
    int r16  = rowBase + wv * 16;

    f16x8 bfrag[4][4];
#pragma unroll
    for (int nt = 0; nt < 4; ++nt)
#pragma unroll
        for (int kc = 0; kc < 4; ++kc)
            bfrag[nt][kc] = *reinterpret_cast<const f16x8*>(&sWt[nt * 16 + mrow][kc * 32 + g * 8]);

    int arow = r16 + mrow;
    const float* xr = x + (size_t)(arow < N ? arow : N - 1) * CIN;
    float4 xa[4][2];
#pragma unroll
    for (int kc = 0; kc < 4; ++kc) {
        xa[kc][0] = *reinterpret_cast<const float4*>(xr + kc * 32 + g * 8);
        xa[kc][1] = *reinterpret_cast<const float4*>(xr + kc * 32 + g * 8 + 4);
    }

    f32x4 acc[4] = {};
#pragma unroll
    for (int kc = 0; kc < 4; ++kc) {
        f16x8 a;
        a[0] = (f16)xa[kc][0].x; a[1] = (f16)xa[kc][0].y;
        a[2] = (f16)xa[kc][0].z; a[3] = (f16)xa[kc][0].w;
        a[4] = (f16)xa[kc][1].x; a[5] = (f16)xa[kc][1].y;
        a[6] = (f16)xa[kc][1].z; a[7] = (f16)xa[kc][1].w;
#pragma unroll
        for (int nt = 0; nt < 4; ++nt)
            acc[nt] = __builtin_amdgcn_mfma_f32_16x16x32_f16(a, bfrag[nt][kc], acc[nt], 0, 0, 0);
    }

#pragma unroll
    for (int nt = 0; nt < 4; ++nt) {
        int c = nt * 16 + mrow;
        float as_w = att[(c >> 3) * 16 + (c & 7)];
        float at_w = att[(c >> 3) * 16 + 8 + (c & 7)];
#pragma unroll
        for (int q = 0; q < 4; ++q) {
            int n = r16 + g * 4 + q;
            float v = acc[nt][q];
            if (n < N) h[(size_t)n * HC + c] = (f16)v;
            float vs = v * as_w, vt = v * at_w;
            vs += __shfl_xor(vs, 1); vs += __shfl_xor(vs, 2); vs += __shfl_xor(vs, 4);
            vt += __shfl_xor(vt, 1); vt += __shfl_xor(vt, 2); vt += __shfl_xor(vt, 4);
            if ((lane & 7) == 0 && n < N) {
                asrc[n * 8 + (c >> 3)] = vs;
                atgt[n * 8 + (c >> 3)] = vt;
            }
        }
    }
}

// ---- fused P4 + gather: 2-pass segment streaming, degree-ordered gather ---
__global__ __launch_bounds__(256) void p4_gather(
    const int* __restrict__ pairs, const int* __restrict__ offs,
    const f16* __restrict__ h, const float* __restrict__ asrc,
    const float* __restrict__ atgt, const float* __restrict__ bias,
    float* __restrict__ out, int N, int E, int EPB)
{
    __shared__ int segB[PBLK], segL[PBLK], segO[PBLK];
    __shared__ int hist[BNODES], scanS[BNODES], fill[BNODES], order[BNODES];
    __shared__ int h2[64], s2[64];
    __shared__ int csrL[CSR_CAP];

    int b   = blockIdx.x;
    int tid = threadIdx.x;
    int bN0 = b << BSH;

    // segment descriptor for partition block `tid`, bucket `b`
    int o0 = offs[(size_t)tid * OSTR + b];
    int o1 = offs[(size_t)tid * OSTR + b + 1];
    int myB = tid * EPB + o0;
    int myL = o1 - o0;
    segB[tid] = myB;
    segL[tid] = myL;
    segO[tid] = myL;
    __syncthreads();
    for (int d = 1; d < PBLK; d <<= 1) {
        int t = (tid >= d) ? segO[tid - d] : 0;
        __syncthreads();
        segO[tid] += t;
        __syncthreads();
    }
    int size = segO[PBLK - 1];
    int myO  = segO[tid] - myL;
    bool lds_ok = (size <= CSR_CAP);

    unsigned lh8 = tid & 7;
    unsigned c0  = lh8 * 8u;

#define EDGE_ACC(S)                                                           \
    { unsigned Su = (unsigned)(S);                                            \
      float Aa = asrc[Su * 8u + lh8] + at;                                    \
      f16x8 Hh = *reinterpret_cast<const f16x8*>(&h[Su * 64u + c0]);          \
      Aa = fmaxf(Aa, NEG_SLOPE * Aa);                                         \
      float Ww = __expf(Aa);                                                  \
      ssum += Ww;                                                             \
      _Pragma("unroll")                                                       \
      for (int i = 0; i < 8; ++i) acc[i] += Ww * (float)Hh[i]; }

#define WRITE_OUT(NODE)                                                       \
    { float inv = 1.f / fmaxf(ssum, EPS_F);                                   \
      float4 b0 = *reinterpret_cast<const float4*>(&bias[c0]);                \
      float4 b1 = *reinterpret_cast<const float4*>(&bias[c0 + 4]);            \
      float4 o0v, o1v;                                                        \
      o0v.x = acc[0] * inv + b0.x; o0v.y = acc[1] * inv + b0.y;               \
      o0v.z = acc[2] * inv + b0.z; o0v.w = acc[3] * inv + b0.w;               \
      o1v.x = acc[4] * inv + b1.x; o1v.y = acc[5] * inv + b1.y;               \
      o1v.z = acc[6] * inv + b1.z; o1v.w = acc[7] * inv + b1.w;               \
      float* op = &out[(size_t)(NODE) * HC + c0];                             \
      *reinterpret_cast<float4*>(op)     = o0v;                               \
      *reinterpret_cast<float4*>(op + 4) = o1v; }

    if (lds_ok) {
        if (tid < BNODES) { hist[tid] = 0; fill[tid] = 0; }
        else if (tid < BNODES + 64) h2[tid - BNODES] = 0;
        __syncthreads();

        // pass A: node-degree histogram from global segment (4-unrolled)
        {
            int i = myB, e = myB + myL;
            for (; i + 4 <= e; i += 4) {
                int p0 = pairs[i],     p1 = pairs[i + 1];
                int p2 = pairs[i + 2], p3 = pairs[i + 3];
                atomicAdd(&hist[((unsigned)p0) >> 17], 1);
                atomicAdd(&hist[((unsigned)p1) >> 17], 1);
                atomicAdd(&hist[((unsigned)p2) >> 17], 1);
                atomicAdd(&hist[((unsigned)p3) >> 17], 1);
            }
            for (; i < e; ++i) atomicAdd(&hist[((unsigned)pairs[i]) >> 17], 1);
        }
        __syncthreads();

        int myrank = 0, mybin = 0;
        if (tid < BNODES) {
            scanS[tid] = hist[tid];
            mybin = min(hist[tid], 63);
            myrank = atomicAdd(&h2[mybin], 1);
        }
        __syncthreads();
        for (int d = 1; d < BNODES; d <<= 1) {
            int t = (tid >= (unsigned)d && tid < BNODES) ? scanS[tid - d] : 0;
            __syncthreads();
            if (tid < BNODES) scanS[tid] += t;
            __syncthreads();
        }
        if (tid == 0) {
            int run = 0;
            for (int i = 0; i < 64; ++i) { int t = h2[i]; s2[i] = run; run += t; }
        }
        // pass B: scatter into node-sorted LDS csr
        {
            int i = myB, e = myB + myL;
            for (; i < e; ++i) {
                int p = pairs[i];
                int j = ((unsigned)p) >> 17;
                int r = atomicAdd(&fill[j], 1);
                csrL[scanS[j] - hist[j] + r] = p & 0x1FFFF;
            }
        }
        __syncthreads();
        if (tid < BNODES) order[s2[mybin] + myrank] = tid;
        __syncthreads();

        // gather: 4 passes x 32 degree-adjacent nodes, 8 lanes/node
        for (int g = 0; g < BNODES; g += 32) {
            int ln   = order[g + (tid >> 3)];
            int node = bN0 + ln;
            if (node >= N) continue;
            int k1 = scanS[ln];
            int k  = k1 - hist[ln];
            float at = atgt[(unsigned)node * 8u + lh8];
            float ssum = 0.f;
            float acc[8] = {0.f, 0.f, 0.f, 0.f, 0.f, 0.f, 0.f, 0.f};

            for (; k + 8 <= k1; k += 8) {
                unsigned S0 = (unsigned)csrL[k],     S1 = (unsigned)csrL[k + 1];
                unsigned S2 = (unsigned)csrL[k + 2], S3 = (unsigned)csrL[k + 3];
                unsigned S4 = (unsigned)csrL[k + 4], S5 = (unsigned)csrL[k + 5];
                unsigned S6 = (unsigned)csrL[k + 6], S7 = (unsigned)csrL[k + 7];
                float A0 = asrc[S0 * 8u + lh8], A1 = asrc[S1 * 8u + lh8];
                float A2 = asrc[S2 * 8u + lh8], A3 = asrc[S3 * 8u + lh8];
                float A4 = asrc[S4 * 8u + lh8], A5 = asrc[S5 * 8u + lh8];
                float A6 = asrc[S6 * 8u + lh8], A7 = asrc[S7 * 8u + lh8];
                f16x8 H0 = *reinterpret_cast<const f16x8*>(&h[S0 * 64u + c0]);
                f16x8 H1 = *reinterpret_cast<const f16x8*>(&h[S1 * 64u + c0]);
                f16x8 H2 = *reinterpret_cast<const f16x8*>(&h[S2 * 64u + c0]);
                f16x8 H3 = *reinterpret_cast<const f16x8*>(&h[S3 * 64u + c0]);
                f16x8 H4 = *reinterpret_cast<const f16x8*>(&h[S4 * 64u + c0]);
                f16x8 H5 = *reinterpret_cast<const f16x8*>(&h[S5 * 64u + c0]);
                f16x8 H6 = *reinterpret_cast<const f16x8*>(&h[S6 * 64u + c0]);
                f16x8 H7 = *reinterpret_cast<const f16x8*>(&h[S7 * 64u + c0]);
                A0 += at; A1 += at; A2 += at; A3 += at;
                A4 += at; A5 += at; A6 += at; A7 += at;
                A0 = fmaxf(A0, NEG_SLOPE * A0); A1 = fmaxf(A1, NEG_SLOPE * A1);
                A2 = fmaxf(A2, NEG_SLOPE * A2); A3 = fmaxf(A3, NEG_SLOPE * A3);
                A4 = fmaxf(A4, NEG_SLOPE * A4); A5 = fmaxf(A5, NEG_SLOPE * A5);
                A6 = fmaxf(A6, NEG_SLOPE * A6); A7 = fmaxf(A7, NEG_SLOPE * A7);
                float w0 = __expf(A0), w1 = __expf(A1);
                float w2 = __expf(A2), w3 = __expf(A3);
                float w4 = __expf(A4), w5 = __expf(A5);
                float w6 = __expf(A6), w7 = __expf(A7);
                ssum += ((w0 + w1) + (w2 + w3)) + ((w4 + w5) + (w6 + w7));
#pragma unroll
                for (int i = 0; i < 8; ++i)
                    acc[i] += ((w0 * (float)H0[i] + w1 * (float)H1[i])
                             + (w2 * (float)H2[i] + w3 * (float)H3[i]))
                            + ((w4 * (float)H4[i] + w5 * (float)H5[i])
                             + (w6 * (float)H6[i] + w7 * (float)H7[i]));
            }
            for (; k < k1; ++k) { EDGE_ACC(csrL[k]); }

            WRITE_OUT(node)
        }
    } else {
        // slow correct fallback: scan all segments per node group (never expected)
        for (int g = 0; g < BNODES; g += 32) {
            int ln   = g + (tid >> 3);
            int node = bN0 + ln;
            if (node >= N) continue;
            float at = atgt[(unsigned)node * 8u + lh8];
            float ssum = 0.f;
            float acc[8] = {0.f, 0.f, 0.f, 0.f, 0.f, 0.f, 0.f, 0.f};
            for (int pb = 0; pb < PBLK; ++pb) {
                int B = segB[pb], L = segL[pb];
                for (int i = 0; i < L; ++i) {
                    int p = pairs[B + i];
                    if ((((unsigned)p) >> 17) == (unsigned)ln) { EDGE_ACC(p & 0x1FFFF); }
                }
            }
            WRITE_OUT(node)
        }
    }
}

extern "C" void kernel_launch(void* const* d_in, const int* in_sizes, int n_in,
                              void* d_out, int out_size, void* d_ws, size_t ws_size,
                              hipStream_t stream)
{
    const float* x    = (const float*)d_in[0];
    const int*   ei   = (const int*)d_in[1];
    const float* W    = (const float*)d_in[2];
    const float* att  = (const float*)d_in[3];
    const float* bias = (const float*)d_in[4];
    float* out = (float*)d_out;

    int N = in_sizes[0] / CIN;
    int E = in_sizes[1] / 2;
    const int* src = ei;
    const int* tgt = ei + E;

    // workspace carve-up (~27 MB)
    f16*   h    = (f16*)d_ws;                     // N*64 fp16       (12.8 MB)
    float* asrc = (float*)(h + (size_t)N * HC);   // N*8             (3.2 MB)
    float* atgt = asrc + (size_t)N * 8;           // N*8             (3.2 MB)
    int*   offs = (int*)(atgt + (size_t)N * 8);   // PBLK*OSTR       (1.05 MB)
    int*   pairs = offs + (size_t)PBLK * OSTR;    // E               (6.4 MB)

    int EPB = (E + PBLK - 1) / PBLK;
    int projB = (N + 63) / 64;

    proj_p3<<<PBLK + projB, 256, 0, stream>>>(x, W, att, h, asrc, atgt, N,
                                              src, tgt, offs, pairs, E, EPB);

    p4_gather<<<(N + BNODES - 1) / BNODES, 256, 0, stream>>>(
        pairs, offs, h, asrc, atgt, bias, out, N, E, EPB);
}

// Round 15
// 102.990 us; speedup vs baseline: 1.1189x; 1.0025x over previous
//
#include <hip/hip_runtime.h>
#include <math.h>

#define NEG_SLOPE 0.2f
#define EPS_F 1e-16f
#define CIN 128
#define HC 64
#define BSH 6              // bucket shift: 64 nodes per bucket
#define BNODES 64
#define NBKT 2048          // bucket count (tgt >> 6), max node 131071 (N < 2^17)
#define PBLK 256           // partition blocks
#define OSTR (NBKT + 1)    // offs row stride
#define CSR_CAP 2048       // LDS csr capacity per bucket (avg ~1025, max ~1200)

typedef _Float16 f16;
typedef _Float16 f16x8 __attribute__((ext_vector_type(8)));
typedef float f32x4  __attribute__((ext_vector_type(4)));

// ---- fused: P3 partition (blocks [0,PBLK)) + projection (rest) ------------
// Block-major pairs: block pb owns pairs[pb*EPB ..), sorted by bucket inside.
// Scan-free: region base = pb*EPB; internal offsets via LDS scan (2048 bins).
__global__ __launch_bounds__(256) void proj_p3(
    const float* __restrict__ x, const float* __restrict__ W,
    const float* __restrict__ att, f16* __restrict__ h,
    float* __restrict__ asrc, float* __restrict__ atgt, int N,
    const int* __restrict__ src, const int* __restrict__ tgt,
    int* __restrict__ offs, int* __restrict__ pairs, int E, int EPB)
{
    __shared__ __align__(16) char smem[HC * (CIN + 8) * 2];   // 17408 B union

    if ((int)blockIdx.x < PBLK) {
        // ---- P3 role ----
        int* lh    = (int*)smem;          // [2048] counts -> cursors (8 KB)
        int* scanP = lh + NBKT;           // [256]
        int pb = blockIdx.x, tid = threadIdx.x;
        for (int i = tid; i < NBKT; i += 256) lh[i] = 0;
        __syncthreads();
        int e0 = pb * EPB, e1 = min(E, e0 + EPB), sz = e1 - e0;
        for (int e = e0 + tid; e < e1; e += 256)
            atomicAdd(&lh[((unsigned)tgt[e]) >> BSH], 1);
        __syncthreads();
        // exclusive scan of 2048 bins: 8 bins/thread + 256-wide Hillis-Steele
        int b8 = tid * 8;
        int v[8], s8 = 0;
#pragma unroll
        for (int i = 0; i < 8; ++i) { v[i] = lh[b8 + i]; s8 += v[i]; }
        scanP[tid] = s8;
        __syncthreads();
        for (int d = 1; d < 256; d <<= 1) {
            int t = (tid >= d) ? scanP[tid - d] : 0;
            __syncthreads();
            scanP[tid] += t;
            __syncthreads();
        }
        int base = scanP[tid] - s8;
        __syncthreads();
        {
            int run = base;
            size_t ob = (size_t)pb * OSTR + b8;
#pragma unroll
            for (int i = 0; i < 8; ++i) {
                lh[b8 + i] = run;
                offs[ob + i] = run;
                run += v[i];
            }
        }
        if (tid == 0) offs[(size_t)pb * OSTR + NBKT] = sz;
        __syncthreads();
        // scatter within own contiguous region (L2 absorbs in-window RMW)
        for (int e = e0 + tid; e < e1; e += 256) {
            int t = tgt[e];
            int r = atomicAdd(&lh[((unsigned)t) >> BSH], 1);
            pairs[e0 + r] = src[e] | ((t & (BNODES - 1)) << 17);
        }
        return;
    }

    // ---- proj role ----
    f16 (*sWt)[CIN + 8] = (f16(*)[CIN + 8])smem;
    int rowBase = ((int)blockIdx.x - PBLK) * 64;
    for (int i = threadIdx.x; i < CIN * HC; i += 256) {
        int k = i >> 6, c = i & 63;
        sWt[c][k] = (f16)W[i];
    }
    __syncthreads();

    int lane = threadIdx.x & 63;
    int wv   = threadIdx.x >> 6;
    int mrow = lane & 15, g = lane >> 4;
    int r16  = rowBase + wv * 16;

    f16x8 bfrag[4][4];
#pragma unroll
    for (int nt = 0; nt < 4; ++nt)
#pragma unroll
        for (int kc = 0; kc < 4; ++kc)
            bfrag[nt][kc] = *reinterpret_cast<const f16x8*>(&sWt[nt * 16 + mrow][kc * 32 + g * 8]);

    int arow = r16 + mrow;
    const float* xr = x + (size_t)(arow < N ? arow : N - 1) * CIN;
    float4 xa[4][2];
#pragma unroll
    for (int kc = 0; kc < 4; ++kc) {
        xa[kc][0] = *reinterpret_cast<const float4*>(xr + kc * 32 + g * 8);
        xa[kc][1] = *reinterpret_cast<const float4*>(xr + kc * 32 + g * 8 + 4);
    }

    f32x4 acc[4] = {};
#pragma unroll
    for (int kc = 0; kc < 4; ++kc) {
        f16x8 a;
        a[0] = (f16)xa[kc][0].x; a[1] = (f16)xa[kc][0].y;
        a[2] = (f16)xa[kc][0].z; a[3] = (f16)xa[kc][0].w;
        a[4] = (f16)xa[kc][1].x; a[5] = (f16)xa[kc][1].y;
        a[6] = (f16)xa[kc][1].z; a[7] = (f16)xa[kc][1].w;
#pragma unroll
        for (int nt = 0; nt < 4; ++nt)
            acc[nt] = __builtin_amdgcn_mfma_f32_16x16x32_f16(a, bfrag[nt][kc], acc[nt], 0, 0, 0);
    }

#pragma unroll
    for (int nt = 0; nt < 4; ++nt) {
        int c = nt * 16 + mrow;
        float as_w = att[(c >> 3) * 16 + (c & 7)];
        float at_w = att[(c >> 3) * 16 + 8 + (c & 7)];
#pragma unroll
        for (int q = 0; q < 4; ++q) {
            int n = r16 + g * 4 + q;
            float v = acc[nt][q];
            if (n < N) h[(size_t)n * HC + c] = (f16)v;
            float vs = v * as_w, vt = v * at_w;
            vs += __shfl_xor(vs, 1); vs += __shfl_xor(vs, 2); vs += __shfl_xor(vs, 4);
            vt += __shfl_xor(vt, 1); vt += __shfl_xor(vt, 2); vt += __shfl_xor(vt, 4);
            if ((lane & 7) == 0 && n < N) {
                asrc[n * 8 + (c >> 3)] = vs;
                atgt[n * 8 + (c >> 3)] = vt;
            }
        }
    }
}

// ---- fused P4 + gather: 2-pass segment streaming, degree-ordered gather ---
__global__ __launch_bounds__(256) void p4_gather(
    const int* __restrict__ pairs, const int* __restrict__ offs,
    const f16* __restrict__ h, const float* __restrict__ asrc,
    const float* __restrict__ atgt, const float* __restrict__ bias,
    float* __restrict__ out, int N, int E, int EPB)
{
    __shared__ int segB[PBLK], segL[PBLK], segO[PBLK];
    __shared__ int hist[BNODES], scanS[BNODES], fill[BNODES], order[BNODES];
    __shared__ int h2[64], s2[64];
    __shared__ int csrL[CSR_CAP];

    int b   = blockIdx.x;
    int tid = threadIdx.x;
    int bN0 = b << BSH;

    // segment descriptor for partition block `tid`, bucket `b`
    int o0 = offs[(size_t)tid * OSTR + b];
    int o1 = offs[(size_t)tid * OSTR + b + 1];
    int myB = tid * EPB + o0;
    int myL = o1 - o0;
    segB[tid] = myB;
    segL[tid] = myL;
    segO[tid] = myL;
    __syncthreads();
    for (int d = 1; d < PBLK; d <<= 1) {
        int t = (tid >= d) ? segO[tid - d] : 0;
        __syncthreads();
        segO[tid] += t;
        __syncthreads();
    }
    int size = segO[PBLK - 1];
    bool lds_ok = (size <= CSR_CAP);

    unsigned lh8 = tid & 7;
    unsigned c0  = lh8 * 8u;

#define EDGE_ACC(S)                                                           \
    { unsigned Su = (unsigned)(S);                                            \
      float Aa = asrc[Su * 8u + lh8] + at;                                    \
      f16x8 Hh = *reinterpret_cast<const f16x8*>(&h[Su * 64u + c0]);          \
      Aa = fmaxf(Aa, NEG_SLOPE * Aa);                                         \
      float Ww = __expf(Aa);                                                  \
      ssum += Ww;                                                             \
      _Pragma("unroll")                                                       \
      for (int i = 0; i < 8; ++i) acc[i] += Ww * (float)Hh[i]; }

#define WRITE_OUT(NODE)                                                       \
    { float inv = 1.f / fmaxf(ssum, EPS_F);                                   \
      float4 b0 = *reinterpret_cast<const float4*>(&bias[c0]);                \
      float4 b1 = *reinterpret_cast<const float4*>(&bias[c0 + 4]);            \
      float4 o0v, o1v;                                                        \
      o0v.x = acc[0] * inv + b0.x; o0v.y = acc[1] * inv + b0.y;               \
      o0v.z = acc[2] * inv + b0.z; o0v.w = acc[3] * inv + b0.w;               \
      o1v.x = acc[4] * inv + b1.x; o1v.y = acc[5] * inv + b1.y;               \
      o1v.z = acc[6] * inv + b1.z; o1v.w = acc[7] * inv + b1.w;               \
      float* op = &out[(size_t)(NODE) * HC + c0];                             \
      *reinterpret_cast<float4*>(op)     = o0v;                               \
      *reinterpret_cast<float4*>(op + 4) = o1v; }

    if (lds_ok) {
        if (tid < BNODES) { hist[tid] = 0; fill[tid] = 0; h2[tid] = 0; }
        __syncthreads();

        // pass A: node-degree histogram from global segment
        {
            int i = myB, e = myB + myL;
            for (; i + 4 <= e; i += 4) {
                int p0 = pairs[i],     p1 = pairs[i + 1];
                int p2 = pairs[i + 2], p3 = pairs[i + 3];
                atomicAdd(&hist[((unsigned)p0) >> 17], 1);
                atomicAdd(&hist[((unsigned)p1) >> 17], 1);
                atomicAdd(&hist[((unsigned)p2) >> 17], 1);
                atomicAdd(&hist[((unsigned)p3) >> 17], 1);
            }
            for (; i < e; ++i) atomicAdd(&hist[((unsigned)pairs[i]) >> 17], 1);
        }
        __syncthreads();

        int myrank = 0, mybin = 0;
        if (tid < BNODES) {
            scanS[tid] = hist[tid];
            mybin = min(hist[tid], 63);
            myrank = atomicAdd(&h2[mybin], 1);
        }
        __syncthreads();
        for (int d = 1; d < BNODES; d <<= 1) {
            int t = (tid >= (unsigned)d && tid < BNODES) ? scanS[tid - d] : 0;
            __syncthreads();
            if (tid < BNODES) scanS[tid] += t;
            __syncthreads();
        }
        if (tid == 0) {
            int run = 0;
            for (int i = 0; i < 64; ++i) { int t = h2[i]; s2[i] = run; run += t; }
        }
        // pass B: scatter into node-sorted LDS csr
        {
            int i = myB, e = myB + myL;
            for (; i < e; ++i) {
                int p = pairs[i];
                int j = ((unsigned)p) >> 17;
                int r = atomicAdd(&fill[j], 1);
                csrL[scanS[j] - hist[j] + r] = p & 0x1FFFF;
            }
        }
        __syncthreads();
        if (tid < BNODES) order[s2[mybin] + myrank] = tid;
        __syncthreads();

        // gather: 2 passes x 32 degree-adjacent nodes, 8 lanes/node
        for (int g = 0; g < BNODES; g += 32) {
            int ln   = order[g + (tid >> 3)];
            int node = bN0 + ln;
            if (node >= N) continue;
            int k1 = scanS[ln];
            int k  = k1 - hist[ln];
            float at = atgt[(unsigned)node * 8u + lh8];
            float ssum = 0.f;
            float acc[8] = {0.f, 0.f, 0.f, 0.f, 0.f, 0.f, 0.f, 0.f};

            for (; k + 8 <= k1; k += 8) {
                unsigned S0 = (unsigned)csrL[k],     S1 = (unsigned)csrL[k + 1];
                unsigned S2 = (unsigned)csrL[k + 2], S3 = (unsigned)csrL[k + 3];
                unsigned S4 = (unsigned)csrL[k + 4], S5 = (unsigned)csrL[k + 5];
                unsigned S6 = (unsigned)csrL[k + 6], S7 = (unsigned)csrL[k + 7];
                float A0 = asrc[S0 * 8u + lh8], A1 = asrc[S1 * 8u + lh8];
                float A2 = asrc[S2 * 8u + lh8], A3 = asrc[S3 * 8u + lh8];
                float A4 = asrc[S4 * 8u + lh8], A5 = asrc[S5 * 8u + lh8];
                float A6 = asrc[S6 * 8u + lh8], A7 = asrc[S7 * 8u + lh8];
                f16x8 H0 = *reinterpret_cast<const f16x8*>(&h[S0 * 64u + c0]);
                f16x8 H1 = *reinterpret_cast<const f16x8*>(&h[S1 * 64u + c0]);
                f16x8 H2 = *reinterpret_cast<const f16x8*>(&h[S2 * 64u + c0]);
                f16x8 H3 = *reinterpret_cast<const f16x8*>(&h[S3 * 64u + c0]);
                f16x8 H4 = *reinterpret_cast<const f16x8*>(&h[S4 * 64u + c0]);
                f16x8 H5 = *reinterpret_cast<const f16x8*>(&h[S5 * 64u + c0]);
                f16x8 H6 = *reinterpret_cast<const f16x8*>(&h[S6 * 64u + c0]);
                f16x8 H7 = *reinterpret_cast<const f16x8*>(&h[S7 * 64u + c0]);
                A0 += at; A1 += at; A2 += at; A3 += at;
                A4 += at; A5 += at; A6 += at; A7 += at;
                A0 = fmaxf(A0, NEG_SLOPE * A0); A1 = fmaxf(A1, NEG_SLOPE * A1);
                A2 = fmaxf(A2, NEG_SLOPE * A2); A3 = fmaxf(A3, NEG_SLOPE * A3);
                A4 = fmaxf(A4, NEG_SLOPE * A4); A5 = fmaxf(A5, NEG_SLOPE * A5);
                A6 = fmaxf(A6, NEG_SLOPE * A6); A7 = fmaxf(A7, NEG_SLOPE * A7);
                float w0 = __expf(A0), w1 = __expf(A1);
                float w2 = __expf(A2), w3 = __expf(A3);
                float w4 = __expf(A4), w5 = __expf(A5);
                float w6 = __expf(A6), w7 = __expf(A7);
                ssum += ((w0 + w1) + (w2 + w3)) + ((w4 + w5) + (w6 + w7));
#pragma unroll
                for (int i = 0; i < 8; ++i)
                    acc[i] += ((w0 * (float)H0[i] + w1 * (float)H1[i])
                             + (w2 * (float)H2[i] + w3 * (float)H3[i]))
                            + ((w4 * (float)H4[i] + w5 * (float)H5[i])
                             + (w6 * (float)H6[i] + w7 * (float)H7[i]));
            }
            for (; k < k1; ++k) { EDGE_ACC(csrL[k]); }

            WRITE_OUT(node)
        }
    } else {
        // slow correct fallback: scan all segments per node group (never expected)
        for (int g = 0; g < BNODES; g += 32) {
            int ln   = g + (tid >> 3);
            int node = bN0 + ln;
            if (node >= N) continue;
            float at = atgt[(unsigned)node * 8u + lh8];
            float ssum = 0.f;
            float acc[8] = {0.f, 0.f, 0.f, 0.f, 0.f, 0.f, 0.f, 0.f};
            for (int pb = 0; pb < PBLK; ++pb) {
                int B = segB[pb], L = segL[pb];
                for (int i = 0; i < L; ++i) {
                    int p = pairs[B + i];
                    if ((((unsigned)p) >> 17) == (unsigned)ln) { EDGE_ACC(p & 0x1FFFF); }
                }
            }
            WRITE_OUT(node)
        }
    }
}

extern "C" void kernel_launch(void* const* d_in, const int* in_sizes, int n_in,
                              void* d_out, int out_size, void* d_ws, size_t ws_size,
                              hipStream_t stream)
{
    const float* x    = (const float*)d_in[0];
    const int*   ei   = (const int*)d_in[1];
    const float* W    = (const float*)d_in[2];
    const float* att  = (const float*)d_in[3];
    const float* bias = (const float*)d_in[4];
    float* out = (float*)d_out;

    int N = in_sizes[0] / CIN;
    int E = in_sizes[1] / 2;
    const int* src = ei;
    const int* tgt = ei + E;

    // workspace carve-up (~28 MB)
    f16*   h    = (f16*)d_ws;                     // N*64 fp16       (12.8 MB)
    float* asrc = (float*)(h + (size_t)N * HC);   // N*8             (3.2 MB)
    float* atgt = asrc + (size_t)N * 8;           // N*8             (3.2 MB)
    int*   offs = (int*)(atgt + (size_t)N * 8);   // PBLK*OSTR       (2.1 MB)
    int*   pairs = offs + (size_t)PBLK * OSTR;    // E               (6.4 MB)

    int EPB = (E + PBLK - 1) / PBLK;
    int projB = (N + 63) / 64;

    proj_p3<<<PBLK + projB, 256, 0, stream>>>(x, W, att, h, asrc, atgt, N,
                                              src, tgt, offs, pairs, E, EPB);

    p4_gather<<<(N + BNODES - 1) / BNODES, 256, 0, stream>>>(
        pairs, offs, h, asrc, atgt, bias, out, N, E, EPB);
}

// Round 16
// 97.869 us; speedup vs baseline: 1.1774x; 1.0523x over previous
//
#include <hip/hip_runtime.h>
#include <math.h>

#define NEG_SLOPE 0.2f
#define EPS_F 1e-16f
#define CIN 128
#define HC 64
#define BSH 6              // bucket shift: 64 nodes per bucket
#define BNODES 64
#define NBKT 2048          // bucket count (tgt >> 6), max node 131071 (N < 2^17)
#define PBLK 256           // partition blocks
#define CSR_CAP 2048       // LDS csr capacity per bucket (avg ~1025, max ~1200)
#define RCAP 8             // per-thread register edge cache

typedef _Float16 f16;
typedef _Float16 f16x8 __attribute__((ext_vector_type(8)));
typedef float f32x4  __attribute__((ext_vector_type(4)));

// ---- fused: P3 partition (blocks [0,PBLK)) + projection (rest) ------------
// Block-major pairs: block pb owns pairs[pb*EPB ..), sorted by bucket inside.
// offsT is TRANSPOSED: offsT[bkt*PBLK + pb] (scattered writes hidden under
// proj's compute; gives p4 coalesced descriptor reads).
__global__ __launch_bounds__(256) void proj_p3(
    const float* __restrict__ x, const float* __restrict__ W,
    const float* __restrict__ att, f16* __restrict__ h,
    float* __restrict__ asrc, float* __restrict__ atgt, int N,
    const int* __restrict__ src, const int* __restrict__ tgt,
    int* __restrict__ offsT, int* __restrict__ pairs, int E, int EPB)
{
    __shared__ __align__(16) char smem[HC * (CIN + 8) * 2];   // 17408 B union

    if ((int)blockIdx.x < PBLK) {
        // ---- P3 role ----
        int* lh    = (int*)smem;          // [2048] counts -> cursors (8 KB)
        int* scanP = lh + NBKT;           // [256]
        int pb = blockIdx.x, tid = threadIdx.x;
        for (int i = tid; i < NBKT; i += 256) lh[i] = 0;
        __syncthreads();
        int e0 = pb * EPB, e1 = min(E, e0 + EPB), sz = e1 - e0;
        for (int e = e0 + tid; e < e1; e += 256)
            atomicAdd(&lh[((unsigned)tgt[e]) >> BSH], 1);
        __syncthreads();
        // exclusive scan of 2048 bins: 8 bins/thread + 256-wide Hillis-Steele
        int b8 = tid * 8;
        int v[8], s8 = 0;
#pragma unroll
        for (int i = 0; i < 8; ++i) { v[i] = lh[b8 + i]; s8 += v[i]; }
        scanP[tid] = s8;
        __syncthreads();
        for (int d = 1; d < 256; d <<= 1) {
            int t = (tid >= d) ? scanP[tid - d] : 0;
            __syncthreads();
            scanP[tid] += t;
            __syncthreads();
        }
        int base = scanP[tid] - s8;
        __syncthreads();
        {
            int run = base;
#pragma unroll
            for (int i = 0; i < 8; ++i) {
                lh[b8 + i] = run;
                offsT[(size_t)(b8 + i) * PBLK + pb] = run;   // transposed
                run += v[i];
            }
        }
        if (tid == 0) offsT[(size_t)NBKT * PBLK + pb] = sz;
        __syncthreads();
        // scatter within own contiguous region (L2 absorbs in-window RMW)
        for (int e = e0 + tid; e < e1; e += 256) {
            int t = tgt[e];
            int r = atomicAdd(&lh[((unsigned)t) >> BSH], 1);
            pairs[e0 + r] = src[e] | ((t & (BNODES - 1)) << 17);
        }
        return;
    }

    // ---- proj role ----
    f16 (*sWt)[CIN + 8] = (f16(*)[CIN + 8])smem;
    int rowBase = ((int)blockIdx.x - PBLK) * 64;
    for (int i = threadIdx.x; i < CIN * HC; i += 256) {
        int k = i >> 6, c = i & 63;
        sWt[c][k] = (f16)W[i];
    }
    __syncthreads();

    int lane = threadIdx.x & 63;
    int wv   = threadIdx.x >> 6;
    int mrow = lane & 15, g = lane >> 4;
    int r16  = rowBase + wv * 16;

    f16x8 bfrag[4][4];
#pragma unroll
    for (int nt = 0; nt < 4; ++nt)
#pragma unroll
        for (int kc = 0; kc < 4; ++kc)
            bfrag[nt][kc] = *reinterpret_cast<const f16x8*>(&sWt[nt * 16 + mrow][kc * 32 + g * 8]);

    int arow = r16 + mrow;
    const float* xr = x + (size_t)(arow < N ? arow : N - 1) * CIN;
    float4 xa[4][2];
#pragma unroll
    for (int kc = 0; kc < 4; ++kc) {
        xa[kc][0] = *reinterpret_cast<const float4*>(xr + kc * 32 + g * 8);
        xa[kc][1] = *reinterpret_cast<const float4*>(xr + kc * 32 + g * 8 + 4);
    }

    f32x4 acc[4] = {};
#pragma unroll
    for (int kc = 0; kc < 4; ++kc) {
        f16x8 a;
        a[0] = (f16)xa[kc][0].x; a[1] = (f16)xa[kc][0].y;
        a[2] = (f16)xa[kc][0].z; a[3] = (f16)xa[kc][0].w;
        a[4] = (f16)xa[kc][1].x; a[5] = (f16)xa[kc][1].y;
        a[6] = (f16)xa[kc][1].z; a[7] = (f16)xa[kc][1].w;
#pragma unroll
        for (int nt = 0; nt < 4; ++nt)
            acc[nt] = __builtin_amdgcn_mfma_f32_16x16x32_f16(a, bfrag[nt][kc], acc[nt], 0, 0, 0);
    }

#pragma unroll
    for (int nt = 0; nt < 4; ++nt) {
        int c = nt * 16 + mrow;
        float as_w = att[(c >> 3) * 16 + (c & 7)];
        float at_w = att[(c >> 3) * 16 + 8 + (c & 7)];
#pragma unroll
        for (int q = 0; q < 4; ++q) {
            int n = r16 + g * 4 + q;
            float v = acc[nt][q];
            if (n < N) h[(size_t)n * HC + c] = (f16)v;
            float vs = v * as_w, vt = v * at_w;
            vs += __shfl_xor(vs, 1); vs += __shfl_xor(vs, 2); vs += __shfl_xor(vs, 4);
            vt += __shfl_xor(vt, 1); vt += __shfl_xor(vt, 2); vt += __shfl_xor(vt, 4);
            if ((lane & 7) == 0 && n < N) {
                asrc[n * 8 + (c >> 3)] = vs;
                atgt[n * 8 + (c >> 3)] = vt;
            }
        }
    }
}

// ---- fused P4 + gather: reg-cached single-pass segments, shfl scans -------
__global__ __launch_bounds__(256) void p4_gather(
    const int* __restrict__ pairs, const int* __restrict__ offsT,
    const f16* __restrict__ h, const float* __restrict__ asrc,
    const float* __restrict__ atgt, const float* __restrict__ bias,
    float* __restrict__ out, int N, int E, int EPB)
{
    __shared__ int segB[PBLK], segL[PBLK];
    __shared__ int hist[BNODES], scanS[BNODES], fill[BNODES], order[BNODES];
    __shared__ int h2[64], s2[64];
    __shared__ int wtot[4];
    __shared__ int csrL[CSR_CAP];

    int b   = blockIdx.x;
    int tid = threadIdx.x;
    int bN0 = b << BSH;
    int lane = tid & 63, wid = tid >> 6;

    // coalesced descriptor reads (transposed offs)
    int o0 = offsT[(size_t)b * PBLK + tid];
    int o1 = offsT[(size_t)(b + 1) * PBLK + tid];
    int myB = tid * EPB + o0;
    int myL = o1 - o0;
    segB[tid] = myB;
    segL[tid] = myL;

    // 256-wide exclusive scan of myL: shfl within wave + cross-wave fixup
    int v = myL;
#pragma unroll
    for (int d = 1; d < 64; d <<= 1) {
        int t = __shfl_up(v, d);
        if (lane >= d) v += t;
    }
    if (lane == 63) wtot[wid] = v;
    __syncthreads();
    int pre = 0;
#pragma unroll
    for (int w = 0; w < 4; ++w) pre += (w < wid) ? wtot[w] : 0;
    int size = wtot[0] + wtot[1] + wtot[2] + wtot[3];
    int myO  = v + pre - myL;
    bool lds_ok = (size <= CSR_CAP);

    // register edge cache (single global read of the segment)
    int ebuf[RCAP];
    {
        int Emax = E - 1;
#pragma unroll
        for (int i = 0; i < RCAP; ++i) {
            int idx = myB + ((i < myL) ? i : 0);
            ebuf[i] = pairs[min(idx, Emax)];
        }
    }

    unsigned lh8 = tid & 7;
    unsigned c0  = lh8 * 8u;

#define EDGE_ACC(S)                                                           \
    { unsigned Su = (unsigned)(S);                                            \
      float Aa = asrc[Su * 8u + lh8] + at;                                    \
      f16x8 Hh = *reinterpret_cast<const f16x8*>(&h[Su * 64u + c0]);          \
      Aa = fmaxf(Aa, NEG_SLOPE * Aa);                                         \
      float Ww = __expf(Aa);                                                  \
      ssum += Ww;                                                             \
      _Pragma("unroll")                                                       \
      for (int i = 0; i < 8; ++i) acc[i] += Ww * (float)Hh[i]; }

#define WRITE_OUT(NODE)                                                       \
    { float inv = 1.f / fmaxf(ssum, EPS_F);                                   \
      float4 b0 = *reinterpret_cast<const float4*>(&bias[c0]);                \
      float4 b1 = *reinterpret_cast<const float4*>(&bias[c0 + 4]);            \
      float4 o0v, o1v;                                                        \
      o0v.x = acc[0] * inv + b0.x; o0v.y = acc[1] * inv + b0.y;               \
      o0v.z = acc[2] * inv + b0.z; o0v.w = acc[3] * inv + b0.w;               \
      o1v.x = acc[4] * inv + b1.x; o1v.y = acc[5] * inv + b1.y;               \
      o1v.z = acc[6] * inv + b1.z; o1v.w = acc[7] * inv + b1.w;               \
      float* op = &out[(size_t)(NODE) * HC + c0];                             \
      *reinterpret_cast<float4*>(op)     = o0v;                               \
      *reinterpret_cast<float4*>(op + 4) = o1v; }

    if (lds_ok) {
        if (tid < BNODES) { hist[tid] = 0; fill[tid] = 0; h2[tid] = 0; }
        __syncthreads();

        // pass A: node-degree histogram from register cache
#pragma unroll
        for (int i = 0; i < RCAP; ++i)
            if (i < myL) atomicAdd(&hist[((unsigned)ebuf[i]) >> 17], 1);
        for (int i = RCAP; i < myL; ++i)
            atomicAdd(&hist[((unsigned)pairs[myB + i]) >> 17], 1);
        __syncthreads();

        // 64-wide node scan in wave 0 (shfl, no barriers)
        int myrank = 0, mybin = 0;
        if (tid < BNODES) {
            int hv = hist[tid];
            int sv = hv;
#pragma unroll
            for (int d = 1; d < 64; d <<= 1) {
                int t = __shfl_up(sv, d);
                if (lane >= d) sv += t;
            }
            scanS[tid] = sv;                       // inclusive
            mybin = min(hv, 63);
            myrank = atomicAdd(&h2[mybin], 1);
        }
        __syncthreads();

        if (tid == 0) {
            int run = 0;
            for (int i = 0; i < 64; ++i) { int t = h2[i]; s2[i] = run; run += t; }
        }
        // pass B: scatter into node-sorted LDS csr (from regs)
#pragma unroll
        for (int i = 0; i < RCAP; ++i)
            if (i < myL) {
                int p = ebuf[i];
                int j = ((unsigned)p) >> 17;
                int r = atomicAdd(&fill[j], 1);
                csrL[scanS[j] - hist[j] + r] = p & 0x1FFFF;
            }
        for (int i = RCAP; i < myL; ++i) {
            int p = pairs[myB + i];
            int j = ((unsigned)p) >> 17;
            int r = atomicAdd(&fill[j], 1);
            csrL[scanS[j] - hist[j] + r] = p & 0x1FFFF;
        }
        __syncthreads();
        if (tid < BNODES) order[s2[mybin] + myrank] = tid;
        __syncthreads();

        // gather: 2 passes x 32 degree-adjacent nodes, 8 lanes/node
        for (int g = 0; g < BNODES; g += 32) {
            int ln   = order[g + (tid >> 3)];
            int node = bN0 + ln;
            if (node >= N) continue;
            int k1 = scanS[ln];
            int k  = k1 - hist[ln];
            float at = atgt[(unsigned)node * 8u + lh8];
            float ssum = 0.f;
            float acc[8] = {0.f, 0.f, 0.f, 0.f, 0.f, 0.f, 0.f, 0.f};

            for (; k + 8 <= k1; k += 8) {
                unsigned S0 = (unsigned)csrL[k],     S1 = (unsigned)csrL[k + 1];
                unsigned S2 = (unsigned)csrL[k + 2], S3 = (unsigned)csrL[k + 3];
                unsigned S4 = (unsigned)csrL[k + 4], S5 = (unsigned)csrL[k + 5];
                unsigned S6 = (unsigned)csrL[k + 6], S7 = (unsigned)csrL[k + 7];
                float A0 = asrc[S0 * 8u + lh8], A1 = asrc[S1 * 8u + lh8];
                float A2 = asrc[S2 * 8u + lh8], A3 = asrc[S3 * 8u + lh8];
                float A4 = asrc[S4 * 8u + lh8], A5 = asrc[S5 * 8u + lh8];
                float A6 = asrc[S6 * 8u + lh8], A7 = asrc[S7 * 8u + lh8];
                f16x8 H0 = *reinterpret_cast<const f16x8*>(&h[S0 * 64u + c0]);
                f16x8 H1 = *reinterpret_cast<const f16x8*>(&h[S1 * 64u + c0]);
                f16x8 H2 = *reinterpret_cast<const f16x8*>(&h[S2 * 64u + c0]);
                f16x8 H3 = *reinterpret_cast<const f16x8*>(&h[S3 * 64u + c0]);
                f16x8 H4 = *reinterpret_cast<const f16x8*>(&h[S4 * 64u + c0]);
                f16x8 H5 = *reinterpret_cast<const f16x8*>(&h[S5 * 64u + c0]);
                f16x8 H6 = *reinterpret_cast<const f16x8*>(&h[S6 * 64u + c0]);
                f16x8 H7 = *reinterpret_cast<const f16x8*>(&h[S7 * 64u + c0]);
                A0 += at; A1 += at; A2 += at; A3 += at;
                A4 += at; A5 += at; A6 += at; A7 += at;
                A0 = fmaxf(A0, NEG_SLOPE * A0); A1 = fmaxf(A1, NEG_SLOPE * A1);
                A2 = fmaxf(A2, NEG_SLOPE * A2); A3 = fmaxf(A3, NEG_SLOPE * A3);
                A4 = fmaxf(A4, NEG_SLOPE * A4); A5 = fmaxf(A5, NEG_SLOPE * A5);
                A6 = fmaxf(A6, NEG_SLOPE * A6); A7 = fmaxf(A7, NEG_SLOPE * A7);
                float w0 = __expf(A0), w1 = __expf(A1);
                float w2 = __expf(A2), w3 = __expf(A3);
                float w4 = __expf(A4), w5 = __expf(A5);
                float w6 = __expf(A6), w7 = __expf(A7);
                ssum += ((w0 + w1) + (w2 + w3)) + ((w4 + w5) + (w6 + w7));
#pragma unroll
                for (int i = 0; i < 8; ++i)
                    acc[i] += ((w0 * (float)H0[i] + w1 * (float)H1[i])
                             + (w2 * (float)H2[i] + w3 * (float)H3[i]))
                            + ((w4 * (float)H4[i] + w5 * (float)H5[i])
                             + (w6 * (float)H6[i] + w7 * (float)H7[i]));
            }
            for (; k < k1; ++k) { EDGE_ACC(csrL[k]); }

            WRITE_OUT(node)
        }
    } else {
        // slow correct fallback: scan all segments per node group (never expected)
        for (int g = 0; g < BNODES; g += 32) {
            int ln   = g + (tid >> 3);
            int node = bN0 + ln;
            if (node >= N) continue;
            float at = atgt[(unsigned)node * 8u + lh8];
            float ssum = 0.f;
            float acc[8] = {0.f, 0.f, 0.f, 0.f, 0.f, 0.f, 0.f, 0.f};
            for (int pb = 0; pb < PBLK; ++pb) {
                int B = segB[pb], L = segL[pb];
                for (int i = 0; i < L; ++i) {
                    int p = pairs[B + i];
                    if ((((unsigned)p) >> 17) == (unsigned)ln) { EDGE_ACC(p & 0x1FFFF); }
                }
            }
            WRITE_OUT(node)
        }
    }
}

extern "C" void kernel_launch(void* const* d_in, const int* in_sizes, int n_in,
                              void* d_out, int out_size, void* d_ws, size_t ws_size,
                              hipStream_t stream)
{
    const float* x    = (const float*)d_in[0];
    const int*   ei   = (const int*)d_in[1];
    const float* W    = (const float*)d_in[2];
    const float* att  = (const float*)d_in[3];
    const float* bias = (const float*)d_in[4];
    float* out = (float*)d_out;

    int N = in_sizes[0] / CIN;
    int E = in_sizes[1] / 2;
    const int* src = ei;
    const int* tgt = ei + E;

    // workspace carve-up (~28 MB)
    f16*   h     = (f16*)d_ws;                    // N*64 fp16       (12.8 MB)
    float* asrc  = (float*)(h + (size_t)N * HC);  // N*8             (3.2 MB)
    float* atgt  = asrc + (size_t)N * 8;          // N*8             (3.2 MB)
    int*   offsT = (int*)(atgt + (size_t)N * 8);  // (NBKT+1)*PBLK   (2.1 MB)
    int*   pairs = offsT + (size_t)(NBKT + 1) * PBLK; // E           (6.4 MB)

    int EPB = (E + PBLK - 1) / PBLK;
    int projB = (N + 63) / 64;

    proj_p3<<<PBLK + projB, 256, 0, stream>>>(x, W, att, h, asrc, atgt, N,
                                              src, tgt, offsT, pairs, E, EPB);

    p4_gather<<<(N + BNODES - 1) / BNODES, 256, 0, stream>>>(
        pairs, offsT, h, asrc, atgt, bias, out, N, E, EPB);
}